// Round 11
// baseline (312.436 us; speedup 1.0000x reference)
//
#include <hip/hip_runtime.h>
#include <stdint.h>

typedef unsigned short u16;
typedef __bf16 bf16x8 __attribute__((ext_vector_type(8)));
typedef float f32x4 __attribute__((ext_vector_type(4)));

#define AS1(p) ((const __attribute__((address_space(1))) void*)(p))
#define AS3(p) ((__attribute__((address_space(3))) void*)(p))

__device__ __forceinline__ float b2f(u16 v){
    union { unsigned u; float f; } x; x.u = ((unsigned)v) << 16; return x.f;
}
__device__ __forceinline__ u16 f2b(float f){
    union { float f; unsigned u; } x; x.f = f;
    unsigned r = x.u + 0x7FFFu + ((x.u >> 16) & 1u);
    return (u16)(r >> 16);
}

// ---------------- dtype probe: one block per input tensor (unchanged, proven) ----------------
__global__ __launch_bounds__(256) void probe_kernel(
    const u16* p0,const u16* p1,const u16* p2,const u16* p3,const u16* p4,
    const u16* p5,const u16* p6,const u16* p7,const u16* p8,const u16* p9,
    const u16* p10,const u16* p11,const u16* p12,
    int n0,int n1,int n2,int n3,int n4,int n5,int n6,int n7,int n8,int n9,
    int n10,int n11,int n12, int* flags)
{
    const u16* p; int n;
    switch (blockIdx.x) {
        case 0: p=p0; n=n0; break;   case 1: p=p1; n=n1; break;
        case 2: p=p2; n=n2; break;   case 3: p=p3; n=n3; break;
        case 4: p=p4; n=n4; break;   case 5: p=p5; n=n5; break;
        case 6: p=p6; n=n6; break;   case 7: p=p7; n=n7; break;
        case 8: p=p8; n=n8; break;   case 9: p=p9; n=n9; break;
        case 10: p=p10; n=n10; break; case 11: p=p11; n=n11; break;
        default: p=p12; n=n12; break;
    }
    int pairs = n >> 1; if (pairs > 2048) pairs = 2048;
    int strong = 0, znz = 0, tot = 0;
    for (int k = threadIdx.x; k < pairs; k += 256) {
        u16 lo = p[2*k], hi = p[2*k+1];
        int eh = (hi >> 7) & 0xFF;
        int el = (lo >> 7) & 0xFF;
        if (eh >= 0xF0 || (eh >= 1 && eh <= 0x40)) strong = 1;
        if (el >= 0xF0 || (el >= 1 && el <= 0x40)) strong = 1;
        if (lo == 0 && hi != 0) znz++;
        tot++;
    }
    __shared__ int ss, sz, st;
    if (threadIdx.x == 0) { ss = 0; sz = 0; st = 0; }
    __syncthreads();
    if (strong) atomicOr(&ss, 1);
    if (znz) atomicAdd(&sz, znz);
    atomicAdd(&st, tot);
    __syncthreads();
    if (threadIdx.x == 0) {
        flags[blockIdx.x] = (ss || (2 * sz > st)) ? 1 : 0;
        if (blockIdx.x == 0) flags[15] = 0;
    }
}

// ---------------- convert weight/vector tensors to bf16 (Tf -> f32) in ws (unchanged) -----------
__global__ __launch_bounds__(256) void convert_kernel(
    const void* sWc, const void* sW2, const void* sW1,
    const void* sTa, const void* sBc, const void* sG1, const void* sB1l,
    const void* sTf, const void* sB1, const void* sB2, const void* sG2, const void* sB2l,
    u16* wbase, const int* flags)
{
    int b = blockIdx.x;
    const void* src; u16* dst; int n, fi, lb, tof32 = 0;
    if (b < 128)      { src=sWc; dst=wbase;          n=262144;  fi=2;  lb=b; }
    else if (b < 640) { src=sW2; dst=wbase+262144;   n=1048576; fi=9;  lb=b-128; }
    else if (b >= 643 && b < 651) { src=sW1; dst=wbase+1312256; n=16384; fi=7; lb=b-643; }
    else {
        lb = 0;
        switch (b) {
            case 640: src=sTa;  dst=wbase+1310720; n=512;  fi=1;  break;
            case 641: src=sBc;  dst=wbase+1311232; n=512;  fi=3;  break;
            case 642: src=sB2;  dst=wbase+1311744; n=512;  fi=10; break;
            case 651: src=sB1;  dst=wbase+1328640; n=2048; fi=8;  break;
            case 652: src=sG1;  dst=wbase+1330688; n=512;  fi=4;  break;
            case 653: src=sB1l; dst=wbase+1331200; n=512;  fi=5;  break;
            case 654: src=sG2;  dst=wbase+1331712; n=512;  fi=11; break;
            case 655: src=sB2l; dst=wbase+1332224; n=512;  fi=12; break;
            default:  src=sTf;  dst=wbase+1332736; n=8;    fi=6;  tof32=1; break;
        }
    }
    int i = lb * 256 + threadIdx.x;
    if (i * 8 >= n) return;
    if (tof32) {
        float* fd = (float*)dst;
        if (flags[fi]) {
            const float4* s = (const float4*)src;
            ((float4*)fd)[i*2] = s[i*2]; ((float4*)fd)[i*2+1] = s[i*2+1];
        } else {
            union { uint4 v; u16 h[8]; } sb;
            sb.v = ((const uint4*)src)[i];
            #pragma unroll
            for (int j = 0; j < 8; j++) fd[i*8+j] = b2f(sb.h[j]);
        }
        return;
    }
    if (flags[fi]) {
        const float4* s = (const float4*)src;
        float4 a = s[i*2], c = s[i*2+1];
        union { uint4 v; u16 h[8]; } o;
        o.h[0]=f2b(a.x); o.h[1]=f2b(a.y); o.h[2]=f2b(a.z); o.h[3]=f2b(a.w);
        o.h[4]=f2b(c.x); o.h[5]=f2b(c.y); o.h[6]=f2b(c.z); o.h[7]=f2b(c.w);
        ((uint4*)dst)[i] = o.v;
    } else {
        ((uint4*)dst)[i] = ((const uint4*)src)[i];
    }
}

// ---------------- qgen: q[m,k] = bf16(cos(x[m,k] + theta[k])) — pure streaming ----------------
__global__ __launch_bounds__(256) void qgen_kernel(
    const void* __restrict__ x, const u16* __restrict__ theta,
    u16* __restrict__ q, const int* flags)
{
    const int idx = blockIdx.x * 256 + threadIdx.x;   // octet index, 2,097,152 total
    const int col0 = (idx * 8) & 511;
    union { uint4 v; u16 h[8]; } tb;
    tb.v = *(const uint4*)(theta + col0);
    float xv[8];
    if (flags[0]) {
        const float4* p = (const float4*)x + idx * 2;
        float4 a = p[0], b = p[1];
        xv[0]=a.x; xv[1]=a.y; xv[2]=a.z; xv[3]=a.w;
        xv[4]=b.x; xv[5]=b.y; xv[6]=b.z; xv[7]=b.w;
    } else {
        union { uint4 v; u16 h[8]; } xb;
        xb.v = ((const uint4*)x)[idx];
        #pragma unroll
        for (int e = 0; e < 8; e++) xv[e] = b2f(xb.h[e]);
    }
    union { uint4 v; u16 h[8]; } o;
    #pragma unroll
    for (int e = 0; e < 8; e++) o.h[e] = f2b(__cosf(xv[e] + b2f(tb.h[e])));
    ((uint4*)q)[idx] = o.v;
}

// ======== gemm1 + fused LN1: x1 = LN(q@Wc^T + bc + x); fq = cos(x1[:,:8]+tf) ========
// (R10 exact — untouched this round; gemm2 is this round's structural experiment)
__global__ __launch_bounds__(512, 2) void gemm1_fused(
    const u16* q, const void* __restrict__ x,
    const u16* __restrict__ Wt, const u16* __restrict__ bias,
    const u16* __restrict__ g1, const u16* __restrict__ b1l,
    const float* __restrict__ tf,
    u16* x1out, u16* __restrict__ fqout, const int* flags)
{
    __shared__ __align__(16) u16 As[2][128 * 64];
    __shared__ __align__(16) u16 Bs[2][512 * 64];
    const int K = 512, N = 512;
    const int tid  = threadIdx.x;
    const int lane = tid & 63;
    const int w    = tid >> 6;

    const int m0 = blockIdx.x * 128;

    const int srow = lane >> 3;
    const int scol = ((lane & 7) ^ srow) * 8;
    const int wm = (w >> 2) * 64;
    const int wn = (w & 3) * 128;
    const int fr   = lane & 15;
    const int quad = lane >> 4;
    const int fx   = fr & 7;
    const int isf32 = flags[0];

    f32x4 acc[4][8];
    #pragma unroll
    for (int i = 0; i < 4; i++)
        #pragma unroll
        for (int jj = 0; jj < 8; jj++)
            acc[i][jj] = f32x4{0.f, 0.f, 0.f, 0.f};

    const u16* Abase = q  + (size_t)m0 * K + scol;
    const u16* Bbase = Wt + scol;

    #pragma unroll
    for (int i = 0; i < 2; i++) {
        int c = w * 2 + i;
        int row = c * 8 + srow;
        __builtin_amdgcn_global_load_lds(AS1(Abase + (size_t)row * K),
                                         AS3(&As[0][c * 512]), 16, 0, 0);
    }
    #pragma unroll
    for (int i = 0; i < 8; i++) {
        int c = w * 8 + i;
        int row = c * 8 + srow;
        __builtin_amdgcn_global_load_lds(AS1(Bbase + (size_t)row * K),
                                         AS3(&Bs[0][c * 512]), 16, 0, 0);
    }

    int cur = 0;
    for (int kt = 0; kt < K; kt += 64) {
        __syncthreads();
        if (kt + 64 < K) {
            int nxt = cur ^ 1;
            #pragma unroll
            for (int i = 0; i < 2; i++) {
                int c = w * 2 + i;
                int row = c * 8 + srow;
                __builtin_amdgcn_global_load_lds(
                    AS1(Abase + (size_t)row * K + kt + 64),
                    AS3(&As[nxt][c * 512]), 16, 0, 0);
            }
            #pragma unroll
            for (int i = 0; i < 8; i++) {
                int c = w * 8 + i;
                int row = c * 8 + srow;
                __builtin_amdgcn_global_load_lds(
                    AS1(Bbase + (size_t)row * K + kt + 64),
                    AS3(&Bs[nxt][c * 512]), 16, 0, 0);
            }
        }
        #pragma unroll
        for (int kk = 0; kk < 2; kk++) {
            bf16x8 af[4];
            #pragma unroll
            for (int mi = 0; mi < 4; mi++)
                af[mi] = *(const bf16x8*)(&As[cur][(wm + mi * 16 + fr) * 64 +
                                          (((kk * 4 + quad) ^ fx) * 8)]);
            #pragma unroll
            for (int np = 0; np < 4; np++) {
                bf16x8 bfr[2];
                #pragma unroll
                for (int ni = 0; ni < 2; ni++)
                    bfr[ni] = *(const bf16x8*)(&Bs[cur][(wn + (np * 2 + ni) * 16 + fr) * 64 +
                                               (((kk * 4 + quad) ^ fx) * 8)]);
                #pragma unroll
                for (int mi = 0; mi < 4; mi++)
                    #pragma unroll
                    for (int ni = 0; ni < 2; ni++)
                        acc[mi][np * 2 + ni] = __builtin_amdgcn_mfma_f32_16x16x32_bf16(
                            af[mi], bfr[ni], acc[mi][np * 2 + ni], 0, 0, 0);
            }
        }
        cur ^= 1;
    }

    __syncthreads();
    u16* zt = &Bs[0][0];
    #pragma unroll
    for (int mi = 0; mi < 4; mi++) {
        #pragma unroll
        for (int nq = 0; nq < 8; nq++) {
            int n = wn + nq * 16 + fr;
            float bn = b2f(bias[n]);
            #pragma unroll
            for (int r = 0; r < 4; r++) {
                int lm = wm + mi * 16 + quad * 4 + r;
                float rv = isf32 ? ((const float*)x)[(size_t)(m0 + lm) * N + n]
                                 : b2f(((const u16*)x)[(size_t)(m0 + lm) * N + n]);
                zt[lm * 512 + n] = f2b(acc[mi][nq][r] + bn + rv);
            }
        }
    }
    __syncthreads();

    {
        union { uint4 v; u16 s[8]; } gb, bb;
        gb.v = *(const uint4*)(g1 + lane * 8);
        bb.v = *(const uint4*)(b1l + lane * 8);
        for (int i = 0; i < 16; i++) {
            int row = w * 16 + i;
            union { uint4 v; u16 s[8]; } zb;
            zb.v = ((const uint4*)(zt + row * 512))[lane];
            float xv[8], s = 0.f, ss = 0.f;
            #pragma unroll
            for (int jj = 0; jj < 8; jj++) {
                xv[jj] = b2f(zb.s[jj]); s += xv[jj]; ss += xv[jj] * xv[jj];
            }
            #pragma unroll
            for (int o = 32; o > 0; o >>= 1) { s += __shfl_down(s, o); ss += __shfl_down(ss, o); }
            s = __shfl(s, 0); ss = __shfl(ss, 0);
            float mu = s * (1.f / 512.f);
            float rs = rsqrtf(ss * (1.f / 512.f) - mu * mu + 1e-5f);
            float xn[8];
            union { uint4 v; u16 s[8]; } ob;
            #pragma unroll
            for (int jj = 0; jj < 8; jj++) {
                xn[jj] = (xv[jj] - mu) * rs * b2f(gb.s[jj]) + b2f(bb.s[jj]);
                ob.s[jj] = f2b(xn[jj]);
            }
            ((uint4*)(x1out + (size_t)(m0 + row) * 512))[lane] = ob.v;
            if (lane == 0) {
                #pragma unroll
                for (int jj = 0; jj < 8; jj++)
                    fqout[(size_t)(m0 + row) * 8 + jj] = f2b(__cosf(xn[jj] + tf[jj]));
            }
        }
    }
}

// ======== gemm2 + fused LN2: out = LN(h@W2 + b2 + x1) — counted-vmcnt 3-buf pipeline ========
// THIS ROUND: BK 64->32, Bs TRIPLE-buffered (3x32KB), raw s_barrier + s_waitcnt vmcnt(4)
// (never 0 mid-loop; prefetch distance 2 tiles; last iter peeled w/ vmcnt(0)). W1/b1 staged
// ONCE into LDS so in-loop VM ops are exactly the 4 gload_lds -> static vmcnt counts exact;
// per-step W1/b1 prefetch becomes cheap lgkm. BK=32 makes the bfr swizzle offset
// LOOP-INVARIANT per thread (swz = quad^(fr&3); no kk term) -> VALU cut.
// Race proof: STAGE(t+2) issued only AFTER barrier(t) (all waves finished reading
// buf[(t-1)%3] == target); vmcnt(4)+barrier ensure loads(t) landed before ds_read of
// buf[t%3]; sched_barrier(0) pins both sides of the boundary.
// h-gen identity re-derived for BK=32: out lane (fr,quad) reg r holds k=t*32+quad*8+g*4+r. 
// LDS pool 132KB: Bs 3x16384 u16 | W1lds @49152 (16384) | b1lds @65536 (2048);
// epilogue zt[128][512] aliases pool[0..65536).
__global__ __launch_bounds__(512, 2) void gemm2_fused(
    const u16* __restrict__ fq, const u16* __restrict__ W1, const u16* __restrict__ b1,
    const u16* __restrict__ Wt, const u16* __restrict__ bias,
    const u16* __restrict__ res, const u16* __restrict__ g2, const u16* __restrict__ b2l,
    void* __restrict__ out, const int* flags)
{
    __shared__ __align__(16) u16 pool[67584];
    const int K = 2048, N = 512, NT = 64;
    const int tid  = threadIdx.x;
    const int lane = tid & 63;
    const int w    = tid >> 6;

    const int m0 = blockIdx.x * 128;

    const int wm = (w >> 2) * 64;          // 2 waves per 64-row m-range
    const int wn = (w & 3) * 128;          // 4 n-positions of 128
    const int fr   = lane & 15;
    const int quad = lane >> 4;
    const int isf32 = flags[0];

    u16* W1lds = pool + 49152;
    u16* b1lds = pool + 65536;

    // fq B-frags for h-gen (quad0 lanes hold data) — unchanged layout
    bf16x8 fqf[4];
    #pragma unroll
    for (int mi = 0; mi < 4; mi++) {
        union { uint4 v; bf16x8 b; } z; z.v = uint4{0,0,0,0};
        if (quad == 0) z.v = *(const uint4*)(fq + (size_t)(m0 + wm + mi * 16 + fr) * 8);
        fqf[mi] = z.b;
    }
    const int krow = ((fr >> 2) * 8) + (fr & 3);

    f32x4 acc[4][8];
    #pragma unroll
    for (int i = 0; i < 4; i++)
        #pragma unroll
        for (int jj = 0; jj < 8; jj++)
            acc[i][jj] = f32x4{0.f, 0.f, 0.f, 0.f};

    // ---- prologue staging ----
    // W1 (32KB) -> LDS, linear
    #pragma unroll
    for (int i = 0; i < 4; i++) {
        int c = w * 4 + i;
        __builtin_amdgcn_global_load_lds(AS1(W1 + (size_t)c * 512 + lane * 8),
                                         AS3(W1lds + c * 512), 16, 0, 0);
    }
    // b1 (4KB) -> LDS, linear
    if (w < 4)
        __builtin_amdgcn_global_load_lds(AS1(b1 + (size_t)w * 512 + lane * 8),
                                         AS3(b1lds + w * 512), 16, 0, 0);
    // B tile staging: chunk = 16 rows x 32 cols; lane -> row rr=lane>>2,
    // src octet (lane&3)^(rr&3) (pre-swizzled source, linear LDS dest)
    const int rr = lane >> 2;
    const int soct = (lane & 3) ^ (rr & 3);
    const u16* Bsrc = Wt + (size_t)rr * K + soct * 8;
    auto STAGE = [&](int tt, int bb) {
        #pragma unroll
        for (int i = 0; i < 4; i++) {
            int c = w * 4 + i;
            __builtin_amdgcn_global_load_lds(
                AS1(Bsrc + (size_t)(c * 16) * K + tt * 32),
                AS3(pool + bb * 16384 + c * 512), 16, 0, 0);
        }
    };
    STAGE(0, 0);
    STAGE(1, 1);
    __syncthreads();                       // one full drain at startup

    // prime W1/b1 regs for t=0 (from LDS)
    union { uint4 v; bf16x8 b; } w1c0, w1c1;
    uint2 b1c0, b1c1;
    w1c0.v = uint4{0,0,0,0}; w1c1.v = uint4{0,0,0,0};
    if (quad == 0) {
        w1c0.v = *(const uint4*)(W1lds + (size_t)krow * 8);
        w1c1.v = *(const uint4*)(W1lds + (size_t)(4 + krow) * 8);
    }
    b1c0 = *(const uint2*)(b1lds + quad * 8);
    b1c1 = *(const uint2*)(b1lds + 4 + quad * 8);

    const int rbase = (wn + fr) * 32 + ((quad ^ (fr & 3)) * 8);  // loop-invariant bfr offset

    int bcur = 0, bstage = 2;
    for (int t = 0; t < NT; ++t) {
        __builtin_amdgcn_sched_barrier(0);
        if (t < NT - 1) asm volatile("s_waitcnt vmcnt(4)" ::: "memory");
        else            asm volatile("s_waitcnt vmcnt(0)" ::: "memory");
        __builtin_amdgcn_s_barrier();
        __builtin_amdgcn_sched_barrier(0);
        if (t + 2 < NT) STAGE(t + 2, bstage);

        // ---- h-gen for this step (register-direct, BK=32 identity) ----
        const u16* pb0 = (const u16*)&b1c0;
        const u16* pb1 = (const u16*)&b1c1;
        f32x4 c0 = {b2f(pb0[0]), b2f(pb0[1]), b2f(pb0[2]), b2f(pb0[3])};
        f32x4 c1 = {b2f(pb1[0]), b2f(pb1[1]), b2f(pb1[2]), b2f(pb1[3])};
        bf16x8 af[4];
        #pragma unroll
        for (int mi = 0; mi < 4; mi++) {
            f32x4 hv0 = __builtin_amdgcn_mfma_f32_16x16x32_bf16(w1c0.b, fqf[mi], c0, 0, 0, 0);
            f32x4 hv1 = __builtin_amdgcn_mfma_f32_16x16x32_bf16(w1c1.b, fqf[mi], c1, 0, 0, 0);
            #pragma unroll
            for (int r = 0; r < 4; r++) {
                af[mi][r]     = (__bf16)fmaxf(hv0[r], 0.f);
                af[mi][4 + r] = (__bf16)fmaxf(hv1[r], 0.f);
            }
        }
        // prefetch next step's W1/b1 from LDS (lgkm only — no vmcnt pollution)
        if (t + 1 < NT) {
            if (quad == 0) {
                w1c0.v = *(const uint4*)(W1lds + (size_t)((t + 1) * 32 + krow) * 8);
                w1c1.v = *(const uint4*)(W1lds + (size_t)((t + 1) * 32 + 4 + krow) * 8);
            }
            b1c0 = *(const uint2*)(b1lds + (t + 1) * 32 + quad * 8);
            b1c1 = *(const uint2*)(b1lds + (t + 1) * 32 + 4 + quad * 8);
        }
        // ---- main MFMA over the wave's 128 n ----
        const u16* BsBuf = pool + bcur * 16384;
        __builtin_amdgcn_s_setprio(1);
        #pragma unroll
        for (int np = 0; np < 4; np++) {
            bf16x8 bfr[2];
            #pragma unroll
            for (int ni = 0; ni < 2; ni++)
                bfr[ni] = *(const bf16x8*)(BsBuf + rbase + (np * 2 + ni) * 512);
            #pragma unroll
            for (int mi = 0; mi < 4; mi++)
                #pragma unroll
                for (int ni = 0; ni < 2; ni++)
                    acc[mi][np * 2 + ni] = __builtin_amdgcn_mfma_f32_16x16x32_bf16(
                        af[mi], bfr[ni], acc[mi][np * 2 + ni], 0, 0, 0);
        }
        __builtin_amdgcn_s_setprio(0);
        bcur   = (bcur   == 2) ? 0 : bcur + 1;
        bstage = (bstage == 2) ? 0 : bstage + 1;
    }

    // ============ phase 1: dump z = bf16(acc + b2 + res) into LDS [128][512] ============
    __syncthreads();
    u16* zt = pool;
    #pragma unroll
    for (int mi = 0; mi < 4; mi++) {
        #pragma unroll
        for (int nq = 0; nq < 8; nq++) {
            int n = wn + nq * 16 + fr;
            float bn = b2f(bias[n]);
            #pragma unroll
            for (int r = 0; r < 4; r++) {
                int lm = wm + mi * 16 + quad * 4 + r;
                float v = acc[mi][nq][r] + bn + b2f(res[(size_t)(m0 + lm) * N + n]);
                zt[lm * 512 + n] = f2b(v);
            }
        }
    }
    __syncthreads();

    // ============ phase 2: LN over complete rows in LDS (ln2 verbatim) ============
    {
        union { uint4 v; u16 s[8]; } gb, bb;
        gb.v = *(const uint4*)(g2 + lane * 8);
        bb.v = *(const uint4*)(b2l + lane * 8);
        for (int i = 0; i < 16; i++) {
            int row = w * 16 + i;
            union { uint4 v; u16 s[8]; } zb;
            zb.v = ((const uint4*)(zt + row * 512))[lane];
            float xv[8], s = 0.f, ss = 0.f;
            #pragma unroll
            for (int jj = 0; jj < 8; jj++) {
                xv[jj] = b2f(zb.s[jj]); s += xv[jj]; ss += xv[jj] * xv[jj];
            }
            #pragma unroll
            for (int o = 32; o > 0; o >>= 1) { s += __shfl_down(s, o); ss += __shfl_down(ss, o); }
            s = __shfl(s, 0); ss = __shfl(ss, 0);
            float mu = s * (1.f / 512.f);
            float rs = rsqrtf(ss * (1.f / 512.f) - mu * mu + 1e-5f);
            size_t m = (size_t)(m0 + row);
            if (isf32) {
                float xn[8];
                #pragma unroll
                for (int jj = 0; jj < 8; jj++)
                    xn[jj] = (xv[jj] - mu) * rs * b2f(gb.s[jj]) + b2f(bb.s[jj]);
                float* po = (float*)out + m * N + lane * 8;
                *(float4*)po       = float4{xn[0], xn[1], xn[2], xn[3]};
                *(float4*)(po + 4) = float4{xn[4], xn[5], xn[6], xn[7]};
            } else {
                union { uint4 v; u16 s[8]; } ob;
                #pragma unroll
                for (int jj = 0; jj < 8; jj++)
                    ob.s[jj] = f2b((xv[jj] - mu) * rs * b2f(gb.s[jj]) + b2f(bb.s[jj]));
                ((uint4*)((u16*)out + m * N))[lane] = ob.v;
            }
        }
    }
}

extern "C" void kernel_launch(void* const* d_in, const int* in_sizes, int n_in,
                              void* d_out, int out_size, void* d_ws, size_t ws_size,
                              hipStream_t stream)
{
    u16* ws16 = (u16*)d_ws;
    // ws (u16 elems): W [0,1332752) | flags @1332752 | fq @1332800 (262144)
    //                 x1 @1594944 (16.7M)
    // q aliases x1 (gemm1's epilogue overwrites its own q rows with x1).
    u16* W     = ws16;
    int* flags = (int*)(ws16 + 1332752);
    u16* fq  = ws16 + 1332800;
    u16* x1  = ws16 + 1594944;
    u16* q   = x1;

    const u16*  wWc  = W;
    const u16*  wW2  = W + 262144;
    const u16*  wTa  = W + 1310720;
    const u16*  wBc  = W + 1311232;
    const u16*  wB2  = W + 1311744;
    const u16*  wW1  = W + 1312256;
    const u16*  wB1  = W + 1328640;
    const u16*  wG1  = W + 1330688;
    const u16*  wB1l = W + 1331200;
    const u16*  wG2  = W + 1331712;
    const u16*  wB2l = W + 1332224;
    const float* wTf = (const float*)(W + 1332736);

    probe_kernel<<<13, 256, 0, stream>>>(
        (const u16*)d_in[0], (const u16*)d_in[1], (const u16*)d_in[2],
        (const u16*)d_in[3], (const u16*)d_in[4], (const u16*)d_in[5],
        (const u16*)d_in[6], (const u16*)d_in[7], (const u16*)d_in[8],
        (const u16*)d_in[9], (const u16*)d_in[10], (const u16*)d_in[11],
        (const u16*)d_in[12],
        in_sizes[0], in_sizes[1], in_sizes[2], in_sizes[3], in_sizes[4],
        in_sizes[5], in_sizes[6], in_sizes[7], in_sizes[8], in_sizes[9],
        in_sizes[10], in_sizes[11], in_sizes[12], flags);

    convert_kernel<<<657, 256, 0, stream>>>(
        d_in[2], d_in[9], d_in[7], d_in[1], d_in[3], d_in[4], d_in[5],
        d_in[6], d_in[8], d_in[10], d_in[11], d_in[12], (u16*)W, flags);

    qgen_kernel<<<8192, 256, 0, stream>>>(d_in[0], wTa, q, flags);

    gemm1_fused<<<256, 512, 0, stream>>>(
        q, d_in[0], wWc, wBc, wG1, wB1l, wTf, x1, fq, flags);

    gemm2_fused<<<256, 512, 0, stream>>>(
        fq, wW1, wB1, wW2, wB2, x1, wG2, wB2l, d_out, flags);
}